// Round 1
// baseline (700.886 us; speedup 1.0000x reference)
//
#include <hip/hip_runtime.h>

#define DIM 1024
#define NROWS 65536
#define PICK 12

// -------------------------------------------------------------------------
// ws layout (floats):
//   0      NK  [12][1024]
//   12288  Qr  [12][1024]
//   24576  M   [1024][12]   (zeroed, atomic-accumulated)
//   36864  Rt  [1024][12]   (zeroed, atomic-accumulated)
//   49152  c0  [12] (pad16, zeroed)
//   49168  c1  [12] (pad16, zeroed)
//   49184  cand_v [768]
//   49952  cand_i [768] (int)
//   50720  top_idx [12] (int, pad16)
//   50736  maxv [65536]
// -------------------------------------------------------------------------

// out[j][d] = sum_e emb[idx[j]][e] * W[d][e] + b[d]      (12 x 1024)
__global__ void __launch_bounds__(256)
rows12_kernel(const float* __restrict__ emb, const float* __restrict__ W,
              const float* __restrict__ b, const int* __restrict__ idx,
              float* __restrict__ out) {
    int d = blockIdx.x;
    int t = threadIdx.x;
    int lane = t & 63;
    int q = t >> 6;
    int e0 = q * 256 + lane * 4;
    float4 w4 = *(const float4*)&W[(size_t)d * DIM + e0];
    float part[PICK];
#pragma unroll
    for (int j = 0; j < PICK; ++j) {
        int r = idx[j];
        float4 e4 = *(const float4*)&emb[(size_t)r * DIM + e0];
        part[j] = w4.x * e4.x + w4.y * e4.y + w4.z * e4.z + w4.w * e4.w;
    }
#pragma unroll
    for (int j = 0; j < PICK; ++j) {
        float v = part[j];
        for (int s = 32; s > 0; s >>= 1) v += __shfl_down(v, s, 64);
        part[j] = v;
    }
    __shared__ float red[4][PICK];
    if (lane == 0) {
#pragma unroll
        for (int j = 0; j < PICK; ++j) red[q][j] = part[j];
    }
    __syncthreads();
    if (t < PICK) {
        float s = red[0][t] + red[1][t] + red[2][t] + red[3][t] + b[d];
        out[t * DIM + d] = s;
    }
}

// out[e][j] += sum_d W[d][e] * V[j][d]   and  cvec[j] += sum_d b[d]*V[j][d]
__global__ void __launch_bounds__(256)
colmat_kernel(const float* __restrict__ W, const float* __restrict__ V,
              const float* __restrict__ b, float* __restrict__ out,
              float* __restrict__ cvec) {
    int blk = blockIdx.x;
    int t = threadIdx.x;
    if (blk == 128) {
        float part[PICK];
#pragma unroll
        for (int j = 0; j < PICK; ++j) part[j] = 0.f;
        for (int k = 0; k < 4; ++k) {
            int d = t + k * 256;
            float bv = b[d];
#pragma unroll
            for (int j = 0; j < PICK; ++j) part[j] += bv * V[j * DIM + d];
        }
#pragma unroll
        for (int j = 0; j < PICK; ++j) {
            float v = part[j];
            for (int s = 32; s > 0; s >>= 1) v += __shfl_down(v, s, 64);
            if ((t & 63) == 0) atomicAdd(&cvec[j], v);
        }
        return;
    }
    int eg = blk & 3;
    int dg = blk >> 2;
    int e = eg * 256 + t;
    int d0 = dg * 32;
    __shared__ float Vs[PICK][32];
    for (int i = t; i < PICK * 32; i += 256) {
        int j = i >> 5, dd = i & 31;
        Vs[j][dd] = V[j * DIM + d0 + dd];
    }
    __syncthreads();
    float acc[PICK];
#pragma unroll
    for (int j = 0; j < PICK; ++j) acc[j] = 0.f;
    for (int dd = 0; dd < 32; ++dd) {
        float w = W[(size_t)(d0 + dd) * DIM + e];
#pragma unroll
        for (int j = 0; j < PICK; ++j) acc[j] += w * Vs[j][dd];
    }
#pragma unroll
    for (int j = 0; j < PICK; ++j) atomicAdd(&out[e * PICK + j], acc[j]);
}

// pass structure (R6): grid 512, block 256 (4 waves), 128 rows/block.
// 48 KB sM -> 2 blocks/CU (96 KB LDS), 8 waves/CU = 2 waves/SIMD (was 1).
// Wave = 16 groups of 4 lanes (g=l>>2, s=l&3); group g owns rows
// {rr*16+g, rr=0..1} of its wave's 32. Lane walks cols i*16+s*4 (i=0..63).
// Prefetch depth 2 (cur/nxt/n2): ~32 KB global in flight per CU, vs the
// ~10-12 KB needed at nominal latency -> headroom for loaded latency.
// M chunk (12 ds_read_b128) applied to 2 rows -> LDS traffic 6 KB/iter/CU,
// well under the 128 B/cyc LDS pipe at the 800-cyc/iter BW pace.

__global__ void __launch_bounds__(256, 2)
pass1_kernel(const float* __restrict__ emb, const float* __restrict__ M,
             const float* __restrict__ c0, float* __restrict__ maxv) {
    __shared__ float sM[DIM * PICK];          // 48 KB
    int t = threadIdx.x;
    for (int i = t; i < DIM * PICK / 4; i += 256)
        ((float4*)sM)[i] = ((const float4*)M)[i];
    __syncthreads();

    int l = t & 63, w = t >> 6;
    int g = l >> 2, s = l & 3;
    size_t wbase = (size_t)blockIdx.x * 128 + w * 32;
    const float* rp[2];
    float4 cur[2], nxt[2];
#pragma unroll
    for (int rr = 0; rr < 2; ++rr) {
        rp[rr] = emb + (wbase + rr * 16 + g) * DIM + s * 4;
        cur[rr] = *(const float4*)rp[rr];
        nxt[rr] = *(const float4*)(rp[rr] + 16);
    }
    float cb[PICK];
#pragma unroll
    for (int j = 0; j < PICK; ++j) cb[j] = c0[j];

    float acc[2][PICK];
#pragma unroll
    for (int rr = 0; rr < 2; ++rr)
#pragma unroll
        for (int j = 0; j < PICK; ++j) acc[rr][j] = 0.f;

    for (int i = 0; i < 64; ++i) {
        int ip2 = (i + 2 < 64) ? i + 2 : 63;
        float4 n2[2];
#pragma unroll
        for (int rr = 0; rr < 2; ++rr) n2[rr] = *(const float4*)(rp[rr] + ip2 * 16);
        const float* mb = sM + (size_t)(i * 16 + s * 4) * PICK;
        float4 m[12];
#pragma unroll
        for (int k = 0; k < 12; ++k) m[k] = *(const float4*)(mb + k * 4);
#pragma unroll
        for (int rr = 0; rr < 2; ++rr) {
            float f[4] = {cur[rr].x, cur[rr].y, cur[rr].z, cur[rr].w};
#pragma unroll
            for (int x = 0; x < 4; ++x) {
                float4 a0 = m[3 * x], a1 = m[3 * x + 1], a2 = m[3 * x + 2];
                acc[rr][0] += f[x] * a0.x; acc[rr][1] += f[x] * a0.y;
                acc[rr][2] += f[x] * a0.z; acc[rr][3] += f[x] * a0.w;
                acc[rr][4] += f[x] * a1.x; acc[rr][5] += f[x] * a1.y;
                acc[rr][6] += f[x] * a1.z; acc[rr][7] += f[x] * a1.w;
                acc[rr][8] += f[x] * a2.x; acc[rr][9] += f[x] * a2.y;
                acc[rr][10] += f[x] * a2.z; acc[rr][11] += f[x] * a2.w;
            }
        }
#pragma unroll
        for (int rr = 0; rr < 2; ++rr) { cur[rr] = nxt[rr]; nxt[rr] = n2[rr]; }
    }
#pragma unroll
    for (int rr = 0; rr < 2; ++rr)
#pragma unroll
        for (int j = 0; j < PICK; ++j) {
            acc[rr][j] += __shfl_xor(acc[rr][j], 1, 64);
            acc[rr][j] += __shfl_xor(acc[rr][j], 2, 64);
        }
    float mx[2];
#pragma unroll
    for (int rr = 0; rr < 2; ++rr) {
        float v = acc[rr][0] + cb[0];
#pragma unroll
        for (int j = 1; j < PICK; ++j) v = fmaxf(v, acc[rr][j] + cb[j]);
        mx[rr] = v;
    }
    if (s < 2) maxv[wbase + s * 16 + g] = (s == 0) ? mx[0] : mx[1];
}

__global__ void __launch_bounds__(256, 2)
pass2_kernel(const float* __restrict__ emb, const float* __restrict__ Rt,
             const float* __restrict__ c1, float* __restrict__ out) {
    __shared__ float sM[DIM * PICK];          // 48 KB
    __shared__ float pooled[128];
    int t = threadIdx.x;
    for (int i = t; i < DIM * PICK / 4; i += 256)
        ((float4*)sM)[i] = ((const float4*)Rt)[i];
    __syncthreads();

    int l = t & 63, w = t >> 6;
    int g = l >> 2, s = l & 3;
    size_t bbase = (size_t)blockIdx.x * 128;
    size_t wbase = bbase + w * 32;
    const float* rp[2];
    float4 cur[2], nxt[2];
#pragma unroll
    for (int rr = 0; rr < 2; ++rr) {
        rp[rr] = emb + (wbase + rr * 16 + g) * DIM + s * 4;
        cur[rr] = *(const float4*)rp[rr];
        nxt[rr] = *(const float4*)(rp[rr] + 16);
    }
    float cb[PICK];
#pragma unroll
    for (int j = 0; j < PICK; ++j) cb[j] = c1[j];

    float acc[2][PICK];
#pragma unroll
    for (int rr = 0; rr < 2; ++rr)
#pragma unroll
        for (int j = 0; j < PICK; ++j) acc[rr][j] = 0.f;

    for (int i = 0; i < 64; ++i) {
        int ip2 = (i + 2 < 64) ? i + 2 : 63;
        float4 n2[2];
#pragma unroll
        for (int rr = 0; rr < 2; ++rr) n2[rr] = *(const float4*)(rp[rr] + ip2 * 16);
        const float* mb = sM + (size_t)(i * 16 + s * 4) * PICK;
        float4 m[12];
#pragma unroll
        for (int k = 0; k < 12; ++k) m[k] = *(const float4*)(mb + k * 4);
#pragma unroll
        for (int rr = 0; rr < 2; ++rr) {
            float f[4] = {cur[rr].x, cur[rr].y, cur[rr].z, cur[rr].w};
#pragma unroll
            for (int x = 0; x < 4; ++x) {
                float4 a0 = m[3 * x], a1 = m[3 * x + 1], a2 = m[3 * x + 2];
                acc[rr][0] += f[x] * a0.x; acc[rr][1] += f[x] * a0.y;
                acc[rr][2] += f[x] * a0.z; acc[rr][3] += f[x] * a0.w;
                acc[rr][4] += f[x] * a1.x; acc[rr][5] += f[x] * a1.y;
                acc[rr][6] += f[x] * a1.z; acc[rr][7] += f[x] * a1.w;
                acc[rr][8] += f[x] * a2.x; acc[rr][9] += f[x] * a2.y;
                acc[rr][10] += f[x] * a2.z; acc[rr][11] += f[x] * a2.w;
            }
        }
#pragma unroll
        for (int rr = 0; rr < 2; ++rr) { cur[rr] = nxt[rr]; nxt[rr] = n2[rr]; }
    }
#pragma unroll
    for (int rr = 0; rr < 2; ++rr)
#pragma unroll
        for (int j = 0; j < PICK; ++j) {
            acc[rr][j] += __shfl_xor(acc[rr][j], 1, 64);
            acc[rr][j] += __shfl_xor(acc[rr][j], 2, 64);
        }
    float mx[2];
#pragma unroll
    for (int rr = 0; rr < 2; ++rr) {
        float v = acc[rr][0] + cb[0];
#pragma unroll
        for (int j = 1; j < PICK; ++j) v = fmaxf(v, acc[rr][j] + cb[j]);
        mx[rr] = v;
    }
    if (s < 2) pooled[w * 32 + s * 16 + g] = (s == 0) ? mx[0] : mx[1];
    __syncthreads();

    // phase B: thread t owns col t*4; re-walk the block's 128 rows (L3-hot)
    const float* tp = emb + bbase * DIM + t * 4;
    float4 o = {0.f, 0.f, 0.f, 0.f};
#pragma unroll 8
    for (int r = 0; r < 128; ++r) {
        float p = pooled[r];
        float4 v = *(const float4*)(tp + (size_t)r * DIM);
        o.x += p * v.x; o.y += p * v.y; o.z += p * v.z; o.w += p * v.w;
    }
    atomicAdd(&out[t * 4 + 0], o.x);
    atomicAdd(&out[t * 4 + 1], o.y);
    atomicAdd(&out[t * 4 + 2], o.z);
    atomicAdd(&out[t * 4 + 3], o.w);
}

// local top-12 of each 1024-chunk of maxv, single wave, register-resident,
// barrier-free: element q*64+t is only ever scanned AND cleared by lane t,
// so the winner-clear needs no cross-lane visibility.
__global__ void __launch_bounds__(64)
top12_local(const float* __restrict__ maxv, float* __restrict__ cand_v,
            int* __restrict__ cand_i) {
    int t = threadIdx.x;
    int base = blockIdx.x * 1024;
    float lv[16];
#pragma unroll
    for (int q = 0; q < 16; ++q) lv[q] = maxv[base + q * 64 + t];
    for (int k = 0; k < PICK; ++k) {
        float bv = -3e38f; int bi = 0x7fffffff;
#pragma unroll
        for (int q = 0; q < 16; ++q) {
            int ii = base + q * 64 + t;
            float v = lv[q];
            if (v > bv || (v == bv && ii < bi)) { bv = v; bi = ii; }
        }
#pragma unroll
        for (int sft = 1; sft < 64; sft <<= 1) {
            float ov = __shfl_xor(bv, sft, 64);
            int oi = __shfl_xor(bi, sft, 64);
            if (ov > bv || (ov == bv && oi < bi)) { bv = ov; bi = oi; }
        }
        if (t == 0) {
            cand_v[blockIdx.x * PICK + k] = bv;
            cand_i[blockIdx.x * PICK + k] = bi;
        }
#pragma unroll
        for (int q = 0; q < 16; ++q)
            if (base + q * 64 + t == bi) lv[q] = -3e38f;
    }
}

// merge 768 candidates -> global top-12 indices; single wave, 12 regs/lane.
__global__ void __launch_bounds__(64)
top12_merge(const float* __restrict__ cand_v, const int* __restrict__ cand_i,
            int* __restrict__ top_idx) {
    int t = threadIdx.x;
    float lv[12]; int li[12];
#pragma unroll
    for (int q = 0; q < 12; ++q) {
        lv[q] = cand_v[q * 64 + t];
        li[q] = cand_i[q * 64 + t];
    }
    for (int k = 0; k < PICK; ++k) {
        float bv = -3e38f; int bi = 0x7fffffff; int bs = -1;
#pragma unroll
        for (int q = 0; q < 12; ++q) {
            if (lv[q] > bv || (lv[q] == bv && li[q] < bi)) {
                bv = lv[q]; bi = li[q]; bs = q * 64 + t;
            }
        }
#pragma unroll
        for (int sft = 1; sft < 64; sft <<= 1) {
            float ov = __shfl_xor(bv, sft, 64);
            int oi = __shfl_xor(bi, sft, 64);
            int os = __shfl_xor(bs, sft, 64);
            if (ov > bv || (ov == bv && oi < bi)) { bv = ov; bi = oi; bs = os; }
        }
        if (t == 0) top_idx[k] = bi;
#pragma unroll
        for (int q = 0; q < 12; ++q)
            if (q * 64 + t == bs) lv[q] = -3e38f;
    }
}

extern "C" void kernel_launch(void* const* d_in, const int* in_sizes, int n_in,
                              void* d_out, int out_size, void* d_ws, size_t ws_size,
                              hipStream_t stream) {
    const float* emb = (const float*)d_in[0];
    const float* Wq  = (const float*)d_in[1];
    const float* bq  = (const float*)d_in[2];
    const float* Wk  = (const float*)d_in[3];
    const float* bk  = (const float*)d_in[4];
    const int* indices = (const int*)d_in[5];
    float* out = (float*)d_out;
    float* ws = (float*)d_ws;

    float* NK      = ws;             // 12288
    float* Qr      = ws + 12288;     // 12288
    float* M       = ws + 24576;     // 12288 (zeroed)
    float* Rt      = ws + 36864;     // 12288 (zeroed)
    float* c0      = ws + 49152;     // 16    (zeroed)
    float* c1      = ws + 49168;     // 16    (zeroed)
    float* cand_v  = ws + 49184;     // 768
    int*   cand_i  = (int*)(ws + 49952);   // 768
    int*   top_idx = (int*)(ws + 50720);   // 16
    float* maxv    = ws + 50736;     // 65536

    hipMemsetAsync(M, 0, (size_t)(12288 * 2 + 32) * sizeof(float), stream);
    hipMemsetAsync(out, 0, DIM * sizeof(float), stream);

    rows12_kernel<<<1024, 256, 0, stream>>>(emb, Wk, bk, indices, NK);
    colmat_kernel<<<129, 256, 0, stream>>>(Wq, NK, bq, M, c0);
    pass1_kernel<<<512, 256, 0, stream>>>(emb, M, c0, maxv);
    top12_local<<<64, 64, 0, stream>>>(maxv, cand_v, cand_i);
    top12_merge<<<1, 64, 0, stream>>>(cand_v, cand_i, top_idx);
    rows12_kernel<<<1024, 256, 0, stream>>>(emb, Wq, bq, top_idx, Qr);
    colmat_kernel<<<129, 256, 0, stream>>>(Wk, Qr, bk, Rt, c1);
    pass2_kernel<<<512, 256, 0, stream>>>(emb, Rt, c1, out);
}

// Round 2
// 555.386 us; speedup vs baseline: 1.2620x; 1.2620x over previous
//
#include <hip/hip_runtime.h>

#define DIM 1024
#define NROWS 65536
#define PICK 12

// -------------------------------------------------------------------------
// ws layout (floats):
//   0      NK  [12][1024]
//   12288  Qr  [12][1024]
//   24576  Mt  [12][1024]   (zeroed, atomic-accumulated, TRANSPOSED: [j][e])
//   36864  Rt  [12][1024]   (zeroed, atomic-accumulated, TRANSPOSED: [j][e])
//   49152  c0  [12] (pad16, zeroed)
//   49168  c1  [12] (pad16, zeroed)
//   49184  cand_v [768]
//   49952  cand_i [768] (int)
//   50720  top_idx [12] (int, pad16)
//   50736  maxv [65536]
// -------------------------------------------------------------------------

// out[j][d] = sum_e emb[idx[j]][e] * W[d][e] + b[d]      (12 x 1024)
__global__ void __launch_bounds__(256)
rows12_kernel(const float* __restrict__ emb, const float* __restrict__ W,
              const float* __restrict__ b, const int* __restrict__ idx,
              float* __restrict__ out) {
    int d = blockIdx.x;
    int t = threadIdx.x;
    int lane = t & 63;
    int q = t >> 6;
    int e0 = q * 256 + lane * 4;
    float4 w4 = *(const float4*)&W[(size_t)d * DIM + e0];
    float part[PICK];
#pragma unroll
    for (int j = 0; j < PICK; ++j) {
        int r = idx[j];
        float4 e4 = *(const float4*)&emb[(size_t)r * DIM + e0];
        part[j] = w4.x * e4.x + w4.y * e4.y + w4.z * e4.z + w4.w * e4.w;
    }
#pragma unroll
    for (int j = 0; j < PICK; ++j) {
        float v = part[j];
        for (int s = 32; s > 0; s >>= 1) v += __shfl_down(v, s, 64);
        part[j] = v;
    }
    __shared__ float red[4][PICK];
    if (lane == 0) {
#pragma unroll
        for (int j = 0; j < PICK; ++j) red[q][j] = part[j];
    }
    __syncthreads();
    if (t < PICK) {
        float s = red[0][t] + red[1][t] + red[2][t] + red[3][t] + b[d];
        out[t * DIM + d] = s;
    }
}

// TRANSPOSED output: out[j][e] += sum_d W[d][e] * V[j][d];  cvec[j] += sum_d b[d]*V[j][d]
__global__ void __launch_bounds__(256)
colmat_kernel(const float* __restrict__ W, const float* __restrict__ V,
              const float* __restrict__ b, float* __restrict__ out,
              float* __restrict__ cvec) {
    int blk = blockIdx.x;
    int t = threadIdx.x;
    if (blk == 128) {
        float part[PICK];
#pragma unroll
        for (int j = 0; j < PICK; ++j) part[j] = 0.f;
        for (int k = 0; k < 4; ++k) {
            int d = t + k * 256;
            float bv = b[d];
#pragma unroll
            for (int j = 0; j < PICK; ++j) part[j] += bv * V[j * DIM + d];
        }
#pragma unroll
        for (int j = 0; j < PICK; ++j) {
            float v = part[j];
            for (int s = 32; s > 0; s >>= 1) v += __shfl_down(v, s, 64);
            if ((t & 63) == 0) atomicAdd(&cvec[j], v);
        }
        return;
    }
    int eg = blk & 3;
    int dg = blk >> 2;
    int e = eg * 256 + t;
    int d0 = dg * 32;
    __shared__ float Vs[PICK][32];
    for (int i = t; i < PICK * 32; i += 256) {
        int j = i >> 5, dd = i & 31;
        Vs[j][dd] = V[j * DIM + d0 + dd];
    }
    __syncthreads();
    float acc[PICK];
#pragma unroll
    for (int j = 0; j < PICK; ++j) acc[j] = 0.f;
    for (int dd = 0; dd < 32; ++dd) {
        float w = W[(size_t)(d0 + dd) * DIM + e];
#pragma unroll
        for (int j = 0; j < PICK; ++j) acc[j] += w * Vs[j][dd];
    }
#pragma unroll
    for (int j = 0; j < PICK; ++j) atomicAdd(&out[j * DIM + e], acc[j]);
}

// -------------------------------------------------------------------------
// pass kernels (R7): DRAM-friendly wave-contiguous loads.
// R6 post-mortem: 16x64B-per-wave-load pattern walked all 65536 rows as
// concurrent 64B streams -> DRAM page thrash -> 1.4 TB/s (17.5% peak) with
// all pipes idle. Fix: every global load is 64 lanes x 16B = 1 KB from ONE
// row (one DRAM page). Dot-reduction moves cross-lane:
//   quad butterfly (xor 1,2) -> LDS scratch (16 quad-partials per (j,row)
//   pair, bank-checked, parity double-buffered, 1 barrier) -> lane p sums
//   16 partials for pair p=(j*2+r) -> xor{2,4,8,16} max over j -> lanes 0/1
//   write the row max.
// grid 512, block 256 (4 waves), 63 KB LDS -> 2 blocks/CU, 8 waves/CU.
// Wave owns 32 rows = 16 groups of 2; ping-pong group prefetch (8 KB
// in flight/wave, 64 KB/CU >> 9 KB BW*latency product).
// Budget per CU: HBM 1 MB -> 102K cyc; VALU ~40K/SIMD; LDS pipe ~49K
// -> HBM-bound with >=2x margin on the other pipes.
// -------------------------------------------------------------------------

#define PG(BUF, G, PAR, SINK)                                                 \
  {                                                                           \
    float acc[2][PICK];                                                       \
    _Pragma("unroll") for (int r = 0; r < 2; ++r)                             \
      _Pragma("unroll") for (int j = 0; j < PICK; ++j) acc[r][j] = 0.f;       \
    _Pragma("unroll") for (int c = 0; c < 4; ++c) {                           \
      float4 m4[PICK];                                                        \
      _Pragma("unroll") for (int j = 0; j < PICK; ++j)                        \
        m4[j] = *(const float4*)&sMt[j * DIM + c * 256 + l * 4];              \
      _Pragma("unroll") for (int r = 0; r < 2; ++r) {                         \
        float4 vv = BUF[r][c];                                                \
        _Pragma("unroll") for (int j = 0; j < PICK; ++j)                      \
          acc[r][j] += vv.x * m4[j].x + vv.y * m4[j].y + vv.z * m4[j].z +     \
                       vv.w * m4[j].w;                                        \
      }                                                                       \
    }                                                                         \
    _Pragma("unroll") for (int r = 0; r < 2; ++r)                             \
      _Pragma("unroll") for (int j = 0; j < PICK; ++j) {                      \
        float v1 = acc[r][j];                                                 \
        v1 += __shfl_xor(v1, 1, 64);                                          \
        v1 += __shfl_xor(v1, 2, 64);                                          \
        acc[r][j] = v1;                                                       \
      }                                                                       \
    if ((l & 3) == 0) {                                                       \
      _Pragma("unroll") for (int jh = 0; jh < 6; ++jh) {                      \
        float4 b4 = {acc[0][2 * jh], acc[1][2 * jh], acc[0][2 * jh + 1],      \
                     acc[1][2 * jh + 1]};                                     \
        *(float4*)&scr[PAR][w][q][jh * 4] = b4;                               \
      }                                                                       \
    }                                                                         \
    __syncthreads();                                                          \
    float sum = 0.f;                                                          \
    _Pragma("unroll") for (int qq = 0; qq < 16; ++qq)                         \
      sum += scr[PAR][w][qq][pidx];                                           \
    float vmax = (p < 24) ? sum + cb : -3e38f;                                \
    _Pragma("unroll") for (int mm = 2; mm <= 16; mm <<= 1)                    \
      vmax = fmaxf(vmax, __shfl_xor(vmax, mm, 64));                           \
    if (p < 2) SINK = vmax;                                                   \
  }

__global__ void __launch_bounds__(256, 2)
pass1_kernel(const float* __restrict__ emb, const float* __restrict__ Mt,
             const float* __restrict__ c0, float* __restrict__ maxv) {
    __shared__ __align__(16) float sMt[PICK * DIM];        // 48 KB
    __shared__ __align__(16) float scr[2][4][16][28];      // 14 KB
    int t = threadIdx.x;
    for (int i = t; i < PICK * DIM / 4; i += 256)
        ((float4*)sMt)[i] = ((const float4*)Mt)[i];
    __syncthreads();

    int l = t & 63, w = t >> 6;
    int q = l >> 2;
    int p = l;                       // pair id: p = j*2 + r for p < 24
    int pidx = (p < 24) ? p : 0;     // broadcast-read for idle lanes
    float cb = (p < 24) ? c0[p >> 1] : 0.f;
    size_t wrow = (size_t)blockIdx.x * 128 + (size_t)w * 32;
    const float* base = emb + wrow * DIM + l * 4;

    float4 A[2][4], B[2][4];
#pragma unroll
    for (int r = 0; r < 2; ++r)
#pragma unroll
      for (int c = 0; c < 4; ++c)
        A[r][c] = *(const float4*)(base + (size_t)r * DIM + c * 256);

    for (int gg = 0; gg < 8; ++gg) {
#pragma unroll
        for (int r = 0; r < 2; ++r)
#pragma unroll
          for (int c = 0; c < 4; ++c)
            B[r][c] = *(const float4*)(base + ((size_t)(2 * gg + 1) * 2 + r) * DIM + c * 256);
        PG(A, 2 * gg, 0, maxv[wrow + (2 * gg) * 2 + p]);
        if (gg < 7) {
#pragma unroll
            for (int r = 0; r < 2; ++r)
#pragma unroll
              for (int c = 0; c < 4; ++c)
                A[r][c] = *(const float4*)(base + ((size_t)(2 * gg + 2) * 2 + r) * DIM + c * 256);
        }
        PG(B, 2 * gg + 1, 1, maxv[wrow + (2 * gg + 1) * 2 + p]);
    }
}

__global__ void __launch_bounds__(256, 2)
pass2_kernel(const float* __restrict__ emb, const float* __restrict__ Rt,
             const float* __restrict__ c1, float* __restrict__ out) {
    __shared__ __align__(16) float sMt[PICK * DIM];        // 48 KB
    __shared__ __align__(16) float scr[2][4][16][28];      // 14 KB
    __shared__ float pooled[128];
    int t = threadIdx.x;
    for (int i = t; i < PICK * DIM / 4; i += 256)
        ((float4*)sMt)[i] = ((const float4*)Rt)[i];
    __syncthreads();

    int l = t & 63, w = t >> 6;
    int q = l >> 2;
    int p = l;
    int pidx = (p < 24) ? p : 0;
    float cb = (p < 24) ? c1[p >> 1] : 0.f;
    size_t bbase = (size_t)blockIdx.x * 128;
    size_t wrow = bbase + (size_t)w * 32;
    const float* base = emb + wrow * DIM + l * 4;

    float4 A[2][4], B[2][4];
#pragma unroll
    for (int r = 0; r < 2; ++r)
#pragma unroll
      for (int c = 0; c < 4; ++c)
        A[r][c] = *(const float4*)(base + (size_t)r * DIM + c * 256);

    for (int gg = 0; gg < 8; ++gg) {
#pragma unroll
        for (int r = 0; r < 2; ++r)
#pragma unroll
          for (int c = 0; c < 4; ++c)
            B[r][c] = *(const float4*)(base + ((size_t)(2 * gg + 1) * 2 + r) * DIM + c * 256);
        PG(A, 2 * gg, 0, pooled[w * 32 + (2 * gg) * 2 + p]);
        if (gg < 7) {
#pragma unroll
            for (int r = 0; r < 2; ++r)
#pragma unroll
              for (int c = 0; c < 4; ++c)
                A[r][c] = *(const float4*)(base + ((size_t)(2 * gg + 2) * 2 + r) * DIM + c * 256);
        }
        PG(B, 2 * gg + 1, 1, pooled[w * 32 + (2 * gg + 1) * 2 + p]);
    }
    __syncthreads();

    // phase B: thread t owns cols t*4..t*4+3; wave reads are 1 KB contiguous.
    // Re-walk the block's 128 rows (L2/L3-hot from phase A).
    const float* tp = emb + bbase * DIM + t * 4;
    float4 o = {0.f, 0.f, 0.f, 0.f};
#pragma unroll 8
    for (int r = 0; r < 128; ++r) {
        float pv = pooled[r];
        float4 v = *(const float4*)(tp + (size_t)r * DIM);
        o.x += pv * v.x; o.y += pv * v.y; o.z += pv * v.z; o.w += pv * v.w;
    }
    atomicAdd(&out[t * 4 + 0], o.x);
    atomicAdd(&out[t * 4 + 1], o.y);
    atomicAdd(&out[t * 4 + 2], o.z);
    atomicAdd(&out[t * 4 + 3], o.w);
}

// local top-12 of each 1024-chunk of maxv, single wave, register-resident,
// barrier-free: element q*64+t is only ever scanned AND cleared by lane t.
__global__ void __launch_bounds__(64)
top12_local(const float* __restrict__ maxv, float* __restrict__ cand_v,
            int* __restrict__ cand_i) {
    int t = threadIdx.x;
    int base = blockIdx.x * 1024;
    float lv[16];
#pragma unroll
    for (int q = 0; q < 16; ++q) lv[q] = maxv[base + q * 64 + t];
    for (int k = 0; k < PICK; ++k) {
        float bv = -3e38f; int bi = 0x7fffffff;
#pragma unroll
        for (int q = 0; q < 16; ++q) {
            int ii = base + q * 64 + t;
            float v = lv[q];
            if (v > bv || (v == bv && ii < bi)) { bv = v; bi = ii; }
        }
#pragma unroll
        for (int sft = 1; sft < 64; sft <<= 1) {
            float ov = __shfl_xor(bv, sft, 64);
            int oi = __shfl_xor(bi, sft, 64);
            if (ov > bv || (ov == bv && oi < bi)) { bv = ov; bi = oi; }
        }
        if (t == 0) {
            cand_v[blockIdx.x * PICK + k] = bv;
            cand_i[blockIdx.x * PICK + k] = bi;
        }
#pragma unroll
        for (int q = 0; q < 16; ++q)
            if (base + q * 64 + t == bi) lv[q] = -3e38f;
    }
}

// merge 768 candidates -> global top-12 indices; single wave, 12 regs/lane.
__global__ void __launch_bounds__(64)
top12_merge(const float* __restrict__ cand_v, const int* __restrict__ cand_i,
            int* __restrict__ top_idx) {
    int t = threadIdx.x;
    float lv[12]; int li[12];
#pragma unroll
    for (int q = 0; q < 12; ++q) {
        lv[q] = cand_v[q * 64 + t];
        li[q] = cand_i[q * 64 + t];
    }
    for (int k = 0; k < PICK; ++k) {
        float bv = -3e38f; int bi = 0x7fffffff; int bs = -1;
#pragma unroll
        for (int q = 0; q < 12; ++q) {
            if (lv[q] > bv || (lv[q] == bv && li[q] < bi)) {
                bv = lv[q]; bi = li[q]; bs = q * 64 + t;
            }
        }
#pragma unroll
        for (int sft = 1; sft < 64; sft <<= 1) {
            float ov = __shfl_xor(bv, sft, 64);
            int oi = __shfl_xor(bi, sft, 64);
            int os = __shfl_xor(bs, sft, 64);
            if (ov > bv || (ov == bv && oi < bi)) { bv = ov; bi = oi; bs = os; }
        }
        if (t == 0) top_idx[k] = bi;
#pragma unroll
        for (int q = 0; q < 12; ++q)
            if (q * 64 + t == bs) lv[q] = -3e38f;
    }
}

extern "C" void kernel_launch(void* const* d_in, const int* in_sizes, int n_in,
                              void* d_out, int out_size, void* d_ws, size_t ws_size,
                              hipStream_t stream) {
    const float* emb = (const float*)d_in[0];
    const float* Wq  = (const float*)d_in[1];
    const float* bq  = (const float*)d_in[2];
    const float* Wk  = (const float*)d_in[3];
    const float* bk  = (const float*)d_in[4];
    const int* indices = (const int*)d_in[5];
    float* out = (float*)d_out;
    float* ws = (float*)d_ws;

    float* NK      = ws;             // 12288
    float* Qr      = ws + 12288;     // 12288
    float* Mt      = ws + 24576;     // 12288 (zeroed, transposed [12][1024])
    float* Rt      = ws + 36864;     // 12288 (zeroed, transposed [12][1024])
    float* c0      = ws + 49152;     // 16    (zeroed)
    float* c1      = ws + 49168;     // 16    (zeroed)
    float* cand_v  = ws + 49184;     // 768
    int*   cand_i  = (int*)(ws + 49952);   // 768
    int*   top_idx = (int*)(ws + 50720);   // 16
    float* maxv    = ws + 50736;     // 65536

    hipMemsetAsync(Mt, 0, (size_t)(12288 * 2 + 32) * sizeof(float), stream);
    hipMemsetAsync(out, 0, DIM * sizeof(float), stream);

    rows12_kernel<<<1024, 256, 0, stream>>>(emb, Wk, bk, indices, NK);
    colmat_kernel<<<129, 256, 0, stream>>>(Wq, NK, bq, Mt, c0);
    pass1_kernel<<<512, 256, 0, stream>>>(emb, Mt, c0, maxv);
    top12_local<<<64, 64, 0, stream>>>(maxv, cand_v, cand_i);
    top12_merge<<<1, 64, 0, stream>>>(cand_v, cand_i, top_idx);
    rows12_kernel<<<1024, 256, 0, stream>>>(emb, Wq, bq, top_idx, Qr);
    colmat_kernel<<<129, 256, 0, stream>>>(Wk, Qr, bk, Rt, c1);
    pass2_kernel<<<512, 256, 0, stream>>>(emb, Rt, c1, out);
}

// Round 3
// 555.122 us; speedup vs baseline: 1.2626x; 1.0005x over previous
//
#include <hip/hip_runtime.h>

#define DIM 1024
#define NROWS 65536
#define PICK 12

// -------------------------------------------------------------------------
// ws layout (floats):
//   0      NK  [12][1024]
//   12288  Qr  [12][1024]
//   24576  Mt  [12][1024]   (zeroed, atomic-accumulated, TRANSPOSED: [j][e])
//   36864  Rt  [12][1024]   (zeroed, atomic-accumulated, TRANSPOSED: [j][e])
//   49152  c0  [12] (pad16, zeroed)
//   49168  c1  [12] (pad16, zeroed)
//   49184  cand_v [768]
//   49952  cand_i [768] (int)
//   50720  top_idx [12] (int, pad16)
//   50736  maxv [65536]
// -------------------------------------------------------------------------

// out[j][d] = sum_e emb[idx[j]][e] * W[d][e] + b[d]      (12 x 1024)
__global__ void __launch_bounds__(256)
rows12_kernel(const float* __restrict__ emb, const float* __restrict__ W,
              const float* __restrict__ b, const int* __restrict__ idx,
              float* __restrict__ out) {
    int d = blockIdx.x;
    int t = threadIdx.x;
    int lane = t & 63;
    int q = t >> 6;
    int e0 = q * 256 + lane * 4;
    float4 w4 = *(const float4*)&W[(size_t)d * DIM + e0];
    float part[PICK];
#pragma unroll
    for (int j = 0; j < PICK; ++j) {
        int r = idx[j];
        float4 e4 = *(const float4*)&emb[(size_t)r * DIM + e0];
        part[j] = w4.x * e4.x + w4.y * e4.y + w4.z * e4.z + w4.w * e4.w;
    }
#pragma unroll
    for (int j = 0; j < PICK; ++j) {
        float v = part[j];
        for (int s = 32; s > 0; s >>= 1) v += __shfl_down(v, s, 64);
        part[j] = v;
    }
    __shared__ float red[4][PICK];
    if (lane == 0) {
#pragma unroll
        for (int j = 0; j < PICK; ++j) red[q][j] = part[j];
    }
    __syncthreads();
    if (t < PICK) {
        float s = red[0][t] + red[1][t] + red[2][t] + red[3][t] + b[d];
        out[t * DIM + d] = s;
    }
}

// TRANSPOSED output: out[j][e] += sum_d W[d][e] * V[j][d];  cvec[j] += sum_d b[d]*V[j][d]
__global__ void __launch_bounds__(256)
colmat_kernel(const float* __restrict__ W, const float* __restrict__ V,
              const float* __restrict__ b, float* __restrict__ out,
              float* __restrict__ cvec) {
    int blk = blockIdx.x;
    int t = threadIdx.x;
    if (blk == 128) {
        float part[PICK];
#pragma unroll
        for (int j = 0; j < PICK; ++j) part[j] = 0.f;
        for (int k = 0; k < 4; ++k) {
            int d = t + k * 256;
            float bv = b[d];
#pragma unroll
            for (int j = 0; j < PICK; ++j) part[j] += bv * V[j * DIM + d];
        }
#pragma unroll
        for (int j = 0; j < PICK; ++j) {
            float v = part[j];
            for (int s = 32; s > 0; s >>= 1) v += __shfl_down(v, s, 64);
            if ((t & 63) == 0) atomicAdd(&cvec[j], v);
        }
        return;
    }
    int eg = blk & 3;
    int dg = blk >> 2;
    int e = eg * 256 + t;
    int d0 = dg * 32;
    __shared__ float Vs[PICK][32];
    for (int i = t; i < PICK * 32; i += 256) {
        int j = i >> 5, dd = i & 31;
        Vs[j][dd] = V[j * DIM + d0 + dd];
    }
    __syncthreads();
    float acc[PICK];
#pragma unroll
    for (int j = 0; j < PICK; ++j) acc[j] = 0.f;
    for (int dd = 0; dd < 32; ++dd) {
        float w = W[(size_t)(d0 + dd) * DIM + e];
#pragma unroll
        for (int j = 0; j < PICK; ++j) acc[j] += w * Vs[j][dd];
    }
#pragma unroll
    for (int j = 0; j < PICK; ++j) atomicAdd(&out[j * DIM + e], acc[j]);
}

// -------------------------------------------------------------------------
// pass kernels (R8): R7 + barrier-drain fix.
// R7 post-mortem: each PG ended with __syncthreads(), whose semantics force
// `s_waitcnt vmcnt(0)` before s_barrier -> the 8 just-prefetched global
// loads were DRAINED twice per 2-row group (32x per kernel), serializing
// issue->drain->compute at full loaded HBM latency. But scr is indexed by
// [w] -- each wave only communicates with itself -- so all that's needed is
// a wave-local LDS fence: `s_waitcnt lgkmcnt(0)` + compiler memory clobber.
// That fence does NOT touch vmcnt, so the global prefetch pipeline now
// survives across groups and the kernel should run at HBM pace.
// Budget per CU (16 rows/group-iter): HBM 64 KB -> 6400 cyc; VALU ~2200
// cyc/SIMD; LDS ~3100 cyc -> HBM-bound with >=2x margin.
// -------------------------------------------------------------------------

#define PG(BUF, G, PAR, SINK)                                                 \
  {                                                                           \
    float acc[2][PICK];                                                       \
    _Pragma("unroll") for (int r = 0; r < 2; ++r)                             \
      _Pragma("unroll") for (int j = 0; j < PICK; ++j) acc[r][j] = 0.f;       \
    _Pragma("unroll") for (int c = 0; c < 4; ++c) {                           \
      float4 m4[PICK];                                                        \
      _Pragma("unroll") for (int j = 0; j < PICK; ++j)                        \
        m4[j] = *(const float4*)&sMt[j * DIM + c * 256 + l * 4];              \
      _Pragma("unroll") for (int r = 0; r < 2; ++r) {                         \
        float4 vv = BUF[r][c];                                                \
        _Pragma("unroll") for (int j = 0; j < PICK; ++j)                      \
          acc[r][j] += vv.x * m4[j].x + vv.y * m4[j].y + vv.z * m4[j].z +     \
                       vv.w * m4[j].w;                                        \
      }                                                                       \
    }                                                                         \
    _Pragma("unroll") for (int r = 0; r < 2; ++r)                             \
      _Pragma("unroll") for (int j = 0; j < PICK; ++j) {                      \
        float v1 = acc[r][j];                                                 \
        v1 += __shfl_xor(v1, 1, 64);                                          \
        v1 += __shfl_xor(v1, 2, 64);                                          \
        acc[r][j] = v1;                                                       \
      }                                                                       \
    if ((l & 3) == 0) {                                                       \
      _Pragma("unroll") for (int jh = 0; jh < 6; ++jh) {                      \
        float4 b4 = {acc[0][2 * jh], acc[1][2 * jh], acc[0][2 * jh + 1],      \
                     acc[1][2 * jh + 1]};                                     \
        *(float4*)&scr[PAR][w][q][jh * 4] = b4;                               \
      }                                                                       \
    }                                                                         \
    asm volatile("s_waitcnt lgkmcnt(0)" ::: "memory");                        \
    float sum = 0.f;                                                          \
    _Pragma("unroll") for (int qq = 0; qq < 16; ++qq)                         \
      sum += scr[PAR][w][qq][pidx];                                           \
    float vmax = (p < 24) ? sum + cb : -3e38f;                                \
    _Pragma("unroll") for (int mm = 2; mm <= 16; mm <<= 1)                    \
      vmax = fmaxf(vmax, __shfl_xor(vmax, mm, 64));                           \
    if (p < 2) SINK = vmax;                                                   \
  }

__global__ void __launch_bounds__(256, 2)
pass1_kernel(const float* __restrict__ emb, const float* __restrict__ Mt,
             const float* __restrict__ c0, float* __restrict__ maxv) {
    __shared__ __align__(16) float sMt[PICK * DIM];        // 48 KB
    __shared__ __align__(16) float scr[2][4][16][28];      // 14 KB
    int t = threadIdx.x;
    for (int i = t; i < PICK * DIM / 4; i += 256)
        ((float4*)sMt)[i] = ((const float4*)Mt)[i];
    __syncthreads();

    int l = t & 63, w = t >> 6;
    int q = l >> 2;
    int p = l;                       // pair id: p = j*2 + r for p < 24
    int pidx = (p < 24) ? p : 0;     // broadcast-read for idle lanes
    float cb = (p < 24) ? c0[p >> 1] : 0.f;
    size_t wrow = (size_t)blockIdx.x * 128 + (size_t)w * 32;
    const float* base = emb + wrow * DIM + l * 4;

    float4 A[2][4], B[2][4];
#pragma unroll
    for (int r = 0; r < 2; ++r)
#pragma unroll
      for (int c = 0; c < 4; ++c)
        A[r][c] = *(const float4*)(base + (size_t)r * DIM + c * 256);

    for (int gg = 0; gg < 8; ++gg) {
#pragma unroll
        for (int r = 0; r < 2; ++r)
#pragma unroll
          for (int c = 0; c < 4; ++c)
            B[r][c] = *(const float4*)(base + ((size_t)(2 * gg + 1) * 2 + r) * DIM + c * 256);
        PG(A, 2 * gg, 0, maxv[wrow + (2 * gg) * 2 + p]);
        if (gg < 7) {
#pragma unroll
            for (int r = 0; r < 2; ++r)
#pragma unroll
              for (int c = 0; c < 4; ++c)
                A[r][c] = *(const float4*)(base + ((size_t)(2 * gg + 2) * 2 + r) * DIM + c * 256);
        }
        PG(B, 2 * gg + 1, 1, maxv[wrow + (2 * gg + 1) * 2 + p]);
    }
}

__global__ void __launch_bounds__(256, 2)
pass2_kernel(const float* __restrict__ emb, const float* __restrict__ Rt,
             const float* __restrict__ c1, float* __restrict__ out) {
    __shared__ __align__(16) float sMt[PICK * DIM];        // 48 KB
    __shared__ __align__(16) float scr[2][4][16][28];      // 14 KB
    __shared__ float pooled[128];
    int t = threadIdx.x;
    for (int i = t; i < PICK * DIM / 4; i += 256)
        ((float4*)sMt)[i] = ((const float4*)Rt)[i];
    __syncthreads();

    int l = t & 63, w = t >> 6;
    int q = l >> 2;
    int p = l;
    int pidx = (p < 24) ? p : 0;
    float cb = (p < 24) ? c1[p >> 1] : 0.f;
    size_t bbase = (size_t)blockIdx.x * 128;
    size_t wrow = bbase + (size_t)w * 32;
    const float* base = emb + wrow * DIM + l * 4;

    float4 A[2][4], B[2][4];
#pragma unroll
    for (int r = 0; r < 2; ++r)
#pragma unroll
      for (int c = 0; c < 4; ++c)
        A[r][c] = *(const float4*)(base + (size_t)r * DIM + c * 256);

    for (int gg = 0; gg < 8; ++gg) {
#pragma unroll
        for (int r = 0; r < 2; ++r)
#pragma unroll
          for (int c = 0; c < 4; ++c)
            B[r][c] = *(const float4*)(base + ((size_t)(2 * gg + 1) * 2 + r) * DIM + c * 256);
        PG(A, 2 * gg, 0, pooled[w * 32 + (2 * gg) * 2 + p]);
        if (gg < 7) {
#pragma unroll
            for (int r = 0; r < 2; ++r)
#pragma unroll
              for (int c = 0; c < 4; ++c)
                A[r][c] = *(const float4*)(base + ((size_t)(2 * gg + 2) * 2 + r) * DIM + c * 256);
        }
        PG(B, 2 * gg + 1, 1, pooled[w * 32 + (2 * gg + 1) * 2 + p]);
    }
    __syncthreads();

    // phase B: thread t owns cols t*4..t*4+3; wave reads are 1 KB contiguous.
    // Re-walk the block's 128 rows (L2/L3-hot from phase A).
    const float* tp = emb + bbase * DIM + t * 4;
    float4 o = {0.f, 0.f, 0.f, 0.f};
#pragma unroll 8
    for (int r = 0; r < 128; ++r) {
        float pv = pooled[r];
        float4 v = *(const float4*)(tp + (size_t)r * DIM);
        o.x += pv * v.x; o.y += pv * v.y; o.z += pv * v.z; o.w += pv * v.w;
    }
    atomicAdd(&out[t * 4 + 0], o.x);
    atomicAdd(&out[t * 4 + 1], o.y);
    atomicAdd(&out[t * 4 + 2], o.z);
    atomicAdd(&out[t * 4 + 3], o.w);
}

// local top-12 of each 1024-chunk of maxv, single wave, register-resident,
// barrier-free: element q*64+t is only ever scanned AND cleared by lane t.
__global__ void __launch_bounds__(64)
top12_local(const float* __restrict__ maxv, float* __restrict__ cand_v,
            int* __restrict__ cand_i) {
    int t = threadIdx.x;
    int base = blockIdx.x * 1024;
    float lv[16];
#pragma unroll
    for (int q = 0; q < 16; ++q) lv[q] = maxv[base + q * 64 + t];
    for (int k = 0; k < PICK; ++k) {
        float bv = -3e38f; int bi = 0x7fffffff;
#pragma unroll
        for (int q = 0; q < 16; ++q) {
            int ii = base + q * 64 + t;
            float v = lv[q];
            if (v > bv || (v == bv && ii < bi)) { bv = v; bi = ii; }
        }
#pragma unroll
        for (int sft = 1; sft < 64; sft <<= 1) {
            float ov = __shfl_xor(bv, sft, 64);
            int oi = __shfl_xor(bi, sft, 64);
            if (ov > bv || (ov == bv && oi < bi)) { bv = ov; bi = oi; }
        }
        if (t == 0) {
            cand_v[blockIdx.x * PICK + k] = bv;
            cand_i[blockIdx.x * PICK + k] = bi;
        }
#pragma unroll
        for (int q = 0; q < 16; ++q)
            if (base + q * 64 + t == bi) lv[q] = -3e38f;
    }
}

// merge 768 candidates -> global top-12 indices; single wave, 12 regs/lane.
__global__ void __launch_bounds__(64)
top12_merge(const float* __restrict__ cand_v, const int* __restrict__ cand_i,
            int* __restrict__ top_idx) {
    int t = threadIdx.x;
    float lv[12]; int li[12];
#pragma unroll
    for (int q = 0; q < 12; ++q) {
        lv[q] = cand_v[q * 64 + t];
        li[q] = cand_i[q * 64 + t];
    }
    for (int k = 0; k < PICK; ++k) {
        float bv = -3e38f; int bi = 0x7fffffff; int bs = -1;
#pragma unroll
        for (int q = 0; q < 12; ++q) {
            if (lv[q] > bv || (lv[q] == bv && li[q] < bi)) {
                bv = lv[q]; bi = li[q]; bs = q * 64 + t;
            }
        }
#pragma unroll
        for (int sft = 1; sft < 64; sft <<= 1) {
            float ov = __shfl_xor(bv, sft, 64);
            int oi = __shfl_xor(bi, sft, 64);
            int os = __shfl_xor(bs, sft, 64);
            if (ov > bv || (ov == bv && oi < bi)) { bv = ov; bi = oi; bs = os; }
        }
        if (t == 0) top_idx[k] = bi;
#pragma unroll
        for (int q = 0; q < 12; ++q)
            if (q * 64 + t == bs) lv[q] = -3e38f;
    }
}

extern "C" void kernel_launch(void* const* d_in, const int* in_sizes, int n_in,
                              void* d_out, int out_size, void* d_ws, size_t ws_size,
                              hipStream_t stream) {
    const float* emb = (const float*)d_in[0];
    const float* Wq  = (const float*)d_in[1];
    const float* bq  = (const float*)d_in[2];
    const float* Wk  = (const float*)d_in[3];
    const float* bk  = (const float*)d_in[4];
    const int* indices = (const int*)d_in[5];
    float* out = (float*)d_out;
    float* ws = (float*)d_ws;

    float* NK      = ws;             // 12288
    float* Qr      = ws + 12288;     // 12288
    float* Mt      = ws + 24576;     // 12288 (zeroed, transposed [12][1024])
    float* Rt      = ws + 36864;     // 12288 (zeroed, transposed [12][1024])
    float* c0      = ws + 49152;     // 16    (zeroed)
    float* c1      = ws + 49168;     // 16    (zeroed)
    float* cand_v  = ws + 49184;     // 768
    int*   cand_i  = (int*)(ws + 49952);   // 768
    int*   top_idx = (int*)(ws + 50720);   // 16
    float* maxv    = ws + 50736;     // 65536

    hipMemsetAsync(Mt, 0, (size_t)(12288 * 2 + 32) * sizeof(float), stream);
    hipMemsetAsync(out, 0, DIM * sizeof(float), stream);

    rows12_kernel<<<1024, 256, 0, stream>>>(emb, Wk, bk, indices, NK);
    colmat_kernel<<<129, 256, 0, stream>>>(Wq, NK, bq, Mt, c0);
    pass1_kernel<<<512, 256, 0, stream>>>(emb, Mt, c0, maxv);
    top12_local<<<64, 64, 0, stream>>>(maxv, cand_v, cand_i);
    top12_merge<<<1, 64, 0, stream>>>(cand_v, cand_i, top_idx);
    rows12_kernel<<<1024, 256, 0, stream>>>(emb, Wq, bq, top_idx, Qr);
    colmat_kernel<<<129, 256, 0, stream>>>(Wk, Qr, bk, Rt, c1);
    pass2_kernel<<<512, 256, 0, stream>>>(emb, Rt, c1, out);
}